// Round 2
// baseline (374.465 us; speedup 1.0000x reference)
//
#include <hip/hip_runtime.h>

// DT loss: trilinear lookup of 1M points into a 704x704x64 fp32 distance grid,
// outputs [mean, dist[N]].
//
// History:
//  R1-R2: direct gather, 4 pts/thread, 95us kernel. FETCH=258MB = 1M pts x 4
//         cold 64B lines (grid 127MB >> L2, random point order -> L2 hit ~0).
//         2.8 TB/s random-access ceiling, VALUBusy 2% -> traffic-bound.
//  R3: spatial bucketing. Pass A bins points into 16x16 (x,y) tiles in d_ws
//      (pre-transformed coords + idx). Pass B: one bin per block iteration ->
//      gathers confined to a 74KB grid region -> L2-local, grid streamed ~once
//      (~140MB) instead of 256MB random. Fallback to direct kernel if ws_size
//      too small.
//  R4: identical resubmit (R3 bench hit GPUAcquisitionTimeout, no data).

#define GH 704
#define GW 704
#define GD 64

#define BSH   4                      // 16x16 (x,y) bins
#define NBX   ((GH + 15) >> 4)       // 44
#define NBY   ((GW + 15) >> 4)       // 44
#define NBINS (NBX * NBY)            // 1936
#define CAP   1024                   // slots/bin; avg occupancy ~517, max ~700

// ---------------------------------------------------------------------------
// Shared trilinear core. x0 = min(floor(s), dim-2), w = s - x0 is exactly
// equivalent to the reference clamp (at s = dim-1: w = 1 -> upper corner).
// z1 = z0+1 always -> the z-pair sits in one cache line.
// ---------------------------------------------------------------------------
__device__ __forceinline__ float trilerp(const float* __restrict__ g,
                                         float sx, float sy, float sz)
{
    const int x0 = min((int)sx, GH - 2);
    const int y0 = min((int)sy, GW - 2);
    const int z0 = min((int)sz, GD - 2);
    const float wx = sx - (float)x0;
    const float wy = sy - (float)y0;
    const float wz = sz - (float)z0;

    const float* p00 = g + ((size_t)x0 * GW + (size_t)y0) * GD + z0;
    const float* p01 = p00 + GD;              // (x0, y0+1)
    const float* p10 = p00 + (size_t)GW * GD; // (x0+1, y0)
    const float* p11 = p10 + GD;              // (x0+1, y0+1)

    const float c000 = p00[0], c001 = p00[1];
    const float c010 = p01[0], c011 = p01[1];
    const float c100 = p10[0], c101 = p10[1];
    const float c110 = p11[0], c111 = p11[1];

    const float c00 = c000 * (1.0f - wz) + c001 * wz;
    const float c01 = c010 * (1.0f - wz) + c011 * wz;
    const float c10 = c100 * (1.0f - wz) + c101 * wz;
    const float c11 = c110 * (1.0f - wz) + c111 * wz;
    const float c0  = c00 * (1.0f - wy) + c01 * wy;
    const float c1  = c10 * (1.0f - wy) + c11 * wy;
    return c0 * (1.0f - wx) + c1 * wx;
}

// ---------------------------------------------------------------------------
// Pass A: transform points, scatter (sx,sy,sz,idx) into spatial bins.
// Overflow list is sized N -> no point can ever be dropped.
// ---------------------------------------------------------------------------
__global__ __launch_bounds__(256) void bin_scatter(
    const float* __restrict__ pc1,
    const float* __restrict__ flow,
    const float* __restrict__ grid_min,
    const int* __restrict__ grid_factor,
    int* __restrict__ cnt,          // [NBINS], pre-zeroed
    int* __restrict__ ovf_cnt,      // [1], pre-zeroed
    float4* __restrict__ slots,     // [NBINS*CAP]
    float4* __restrict__ ovf,       // [N]
    int N)
{
    const int i = blockIdx.x * blockDim.x + threadIdx.x;
    if (i >= N) return;

    const float gf  = (float)(*grid_factor);
    float sx = (pc1[3 * i + 0] + flow[3 * i + 0] - grid_min[0]) * gf;
    float sy = (pc1[3 * i + 1] + flow[3 * i + 1] - grid_min[1]) * gf;
    float sz = (pc1[3 * i + 2] + flow[3 * i + 2] - grid_min[2]) * gf;
    sx = fminf(fmaxf(sx, 0.0f), (float)(GH - 1));
    sy = fminf(fmaxf(sy, 0.0f), (float)(GW - 1));
    sz = fminf(fmaxf(sz, 0.0f), (float)(GD - 1));

    const int bin = (((int)sx) >> BSH) * NBY + (((int)sy) >> BSH);
    const float4 rec = make_float4(sx, sy, sz, __int_as_float(i));

    const int pos = atomicAdd(&cnt[bin], 1);
    if (pos < CAP) {
        slots[(size_t)bin * CAP + pos] = rec;
    } else {
        const int op = atomicAdd(ovf_cnt, 1);  // op < N always
        ovf[op] = rec;
    }
}

// ---------------------------------------------------------------------------
// Pass B: one bin at a time per block -> gathers hit a 17x17x64 = 74KB grid
// region (L2-resident). 512 blocks = 2/CU keeps per-XCD concurrent region
// footprint ~= 4MB L2. Overflow points handled by the same kernel (grid-stride)
// — typically zero.
// ---------------------------------------------------------------------------
__global__ __launch_bounds__(256, 4) void bin_process(
    const float* __restrict__ grid,
    const int* __restrict__ cnt,
    const int* __restrict__ ovf_cnt,
    const float4* __restrict__ slots,
    const float4* __restrict__ ovf,
    float* __restrict__ out,        // out[0]=mean (pre-zeroed), out[1..N]=dist
    int N)
{
    float acc = 0.0f;

    for (int bin = blockIdx.x; bin < NBINS; bin += gridDim.x) {
        const int n = min(cnt[bin], CAP);
        const float4* sl = slots + (size_t)bin * CAP;
        for (int base = 0; base < n; base += 256) {
            const int t = base + (int)threadIdx.x;
            if (t < n) {
                const float4 s = sl[t];
                const float v = trilerp(grid, s.x, s.y, s.z);
                out[1 + __float_as_int(s.w)] = v;
                acc += v;
            }
        }
    }

    // Overflow tail (usually empty; every block checks, grid-stride).
    const int novf = min(*ovf_cnt, N);
    for (int t = blockIdx.x * 256 + (int)threadIdx.x; t < novf;
         t += gridDim.x * 256) {
        const float4 s = ovf[t];
        const float v = trilerp(grid, s.x, s.y, s.z);
        out[1 + __float_as_int(s.w)] = v;
        acc += v;
    }

    // Mean: wave64 shuffle -> LDS -> one atomic per block.
    float s = acc;
    #pragma unroll
    for (int off = 32; off > 0; off >>= 1)
        s += __shfl_down(s, off, 64);

    __shared__ float wsum[4];
    const int lane = threadIdx.x & 63;
    const int wid  = threadIdx.x >> 6;
    if (lane == 0) wsum[wid] = s;
    __syncthreads();
    if (threadIdx.x == 0) {
        const float part = wsum[0] + wsum[1] + wsum[2] + wsum[3];
        atomicAdd(out, part * (1.0f / (float)N));
    }
}

// ---------------------------------------------------------------------------
// Fallback: R2 direct-gather kernel (used if ws_size is too small).
// ---------------------------------------------------------------------------
#define PTS 4
__global__ __launch_bounds__(256, 4) void dt_loss_kernel(
    const float* __restrict__ pc1,
    const float* __restrict__ flow,
    const float* __restrict__ grid,
    const float* __restrict__ grid_min,
    const int* __restrict__ grid_factor,
    float* __restrict__ out,
    int N)
{
    const int T = gridDim.x * blockDim.x;
    const int i0 = blockIdx.x * blockDim.x + threadIdx.x;

    const float gf = (float)(*grid_factor);
    const float gmx = grid_min[0];
    const float gmy = grid_min[1];
    const float gmz = grid_min[2];

    float acc = 0.0f;
    #pragma unroll
    for (int j = 0; j < PTS; ++j) {
        const int i = i0 + j * T;
        if (i < N) {
            float sx = (pc1[3 * i + 0] + flow[3 * i + 0] - gmx) * gf;
            float sy = (pc1[3 * i + 1] + flow[3 * i + 1] - gmy) * gf;
            float sz = (pc1[3 * i + 2] + flow[3 * i + 2] - gmz) * gf;
            sx = fminf(fmaxf(sx, 0.0f), (float)(GH - 1));
            sy = fminf(fmaxf(sy, 0.0f), (float)(GW - 1));
            sz = fminf(fmaxf(sz, 0.0f), (float)(GD - 1));
            const float v = trilerp(grid, sx, sy, sz);
            out[1 + i] = v;
            acc += v;
        }
    }

    float s = acc;
    #pragma unroll
    for (int off = 32; off > 0; off >>= 1)
        s += __shfl_down(s, off, 64);

    __shared__ float wsum[4];
    const int lane = threadIdx.x & 63;
    const int wid  = threadIdx.x >> 6;
    if (lane == 0) wsum[wid] = s;
    __syncthreads();
    if (threadIdx.x == 0) {
        const float part = wsum[0] + wsum[1] + wsum[2] + wsum[3];
        atomicAdd(out, part * (1.0f / (float)N));
    }
}

extern "C" void kernel_launch(void* const* d_in, const int* in_sizes, int n_in,
                              void* d_out, int out_size, void* d_ws, size_t ws_size,
                              hipStream_t stream) {
    const float* pc1         = (const float*)d_in[0];
    const float* flow        = (const float*)d_in[1];
    const float* grid        = (const float*)d_in[2];
    const float* grid_min    = (const float*)d_in[3];
    const int*   grid_factor = (const int*)d_in[4];
    float* out = (float*)d_out;

    const int N = in_sizes[0] / 3;  // pc1 is [1, N, 3]

    // Workspace layout:
    //   [0 .. NBINS*4)                 : bin counters
    //   [NBINS*4 .. NBINS*4+4)        : overflow counter
    //   [8192 .. 8192+NBINS*CAP*16)   : bin slots (float4)
    //   [.. +N*16)                    : overflow list (float4)
    const size_t slots_bytes = (size_t)NBINS * CAP * sizeof(float4);
    const size_t need = 8192 + slots_bytes + (size_t)N * sizeof(float4);

    hipMemsetAsync(d_out, 0, sizeof(float), stream);

    if (ws_size >= need && N > 0) {
        int*    cnt   = (int*)d_ws;
        int*    ovfc  = (int*)((char*)d_ws + (size_t)NBINS * 4);
        float4* slots = (float4*)((char*)d_ws + 8192);
        float4* ovf   = (float4*)((char*)d_ws + 8192 + slots_bytes);

        hipMemsetAsync(d_ws, 0, (size_t)(NBINS + 1) * 4, stream);

        const int blkA = (N + 255) / 256;
        bin_scatter<<<blkA, 256, 0, stream>>>(
            pc1, flow, grid_min, grid_factor, cnt, ovfc, slots, ovf, N);

        bin_process<<<512, 256, 0, stream>>>(
            grid, cnt, ovfc, slots, ovf, out, N);
    } else {
        const int block = 256;
        const int threads_needed = (N + PTS - 1) / PTS;
        const int grid_sz = (threads_needed + block - 1) / block;
        dt_loss_kernel<<<grid_sz, block, 0, stream>>>(
            pc1, flow, grid, grid_min, grid_factor, out, N);
    }
}

// Round 3
// 247.244 us; speedup vs baseline: 1.5146x; 1.5146x over previous
//
#include <hip/hip_runtime.h>

// DT loss: trilinear lookup of 1M points into a 704x704x64 fp32 distance grid,
// outputs [mean, dist[N]].
//
// History:
//  R1-R2: direct gather, 4 pts/thread, 95us. FETCH=258MB = 1M pts x 4 cold 64B
//         lines (random order, grid 127MB >> L2). 8 separate dword gathers/pt:
//         8M req @ 84G/s AND 4M lines @ 42G/s both saturated - ambiguous cap.
//  R3/R4: spatial bucketing FAILED (374us): pass A = 145us, bound by 1M
//         scattered 16B write granules (~6.9G granules/s) + 1M atomic return
//         chains; ~1 pt/bin/block -> writes can't cluster. Max grid reuse is
//         only 2x (4M touches / 2M lines) -> bucketing can't pay for itself.
//  R5: back to direct gather, but fuse each z-pair (z1 = z0+1 always, same
//      line) into ONE dwordx2 load -> 4 requests/pt instead of 8, same 4
//      lines. Discriminates request-rate vs line-rate ceiling; free upside.

#define GH 704
#define GW 704
#define GD 64
#define PTS 4

__global__ __launch_bounds__(256, 4) void dt_loss_kernel(
    const float* __restrict__ pc1,
    const float* __restrict__ flow,
    const float* __restrict__ grid,
    const float* __restrict__ grid_min,
    const int* __restrict__ grid_factor,
    float* __restrict__ out,   // out[0] = mean (pre-zeroed), out[1..N] = dist
    int N)
{
    const int T = gridDim.x * blockDim.x;       // total threads
    const int i0 = blockIdx.x * blockDim.x + threadIdx.x;

    const float gf = (float)(*grid_factor);
    const float gmx = grid_min[0];
    const float gmy = grid_min[1];
    const float gmz = grid_min[2];

    // ---- Phase 1: load all PTS points' coords (coalesced, independent) ----
    float px[PTS], py[PTS], pz[PTS];
    bool  act[PTS];
    #pragma unroll
    for (int j = 0; j < PTS; ++j) {
        const int i = i0 + j * T;
        act[j] = (i < N);
        const int ii = act[j] ? i : 0;
        px[j] = pc1[3 * ii + 0] + flow[3 * ii + 0];
        py[j] = pc1[3 * ii + 1] + flow[3 * ii + 1];
        pz[j] = pc1[3 * ii + 2] + flow[3 * ii + 2];
    }

    // ---- Phase 2: addresses + issue all gathers (16 dwordx2 in flight) ----
    // z0 = min(floor(sz), GD-2), wz = sz - z0 is exactly equivalent to the
    // reference clamp (at sz = GD-1: wz = 1 selects the upper corner), and
    // makes the z-pair a single contiguous 8B load.
    float wx[PTS], wy[PTS], wz[PTS];
    float2 v00[PTS], v01[PTS], v10[PTS], v11[PTS];
    #pragma unroll
    for (int j = 0; j < PTS; ++j) {
        float sx = (px[j] - gmx) * gf;
        float sy = (py[j] - gmy) * gf;
        float sz = (pz[j] - gmz) * gf;
        sx = fminf(fmaxf(sx, 0.0f), (float)(GH - 1));
        sy = fminf(fmaxf(sy, 0.0f), (float)(GW - 1));
        sz = fminf(fmaxf(sz, 0.0f), (float)(GD - 1));

        const int x0 = min((int)sx, GH - 2);
        const int y0 = min((int)sy, GW - 2);
        const int z0 = min((int)sz, GD - 2);

        wx[j] = sx - (float)x0;
        wy[j] = sy - (float)y0;
        wz[j] = sz - (float)z0;

        const float* p00 = grid + ((size_t)x0 * GW + (size_t)y0) * GD + z0;
        const float* p01 = p00 + GD;              // (x0, y0+1)
        const float* p10 = p00 + (size_t)GW * GD; // (x0+1, y0)
        const float* p11 = p10 + GD;              // (x0+1, y0+1)

        __builtin_memcpy(&v00[j], p00, 8);  // {c000, c001}
        __builtin_memcpy(&v01[j], p01, 8);  // {c010, c011}
        __builtin_memcpy(&v10[j], p10, 8);  // {c100, c101}
        __builtin_memcpy(&v11[j], p11, 8);  // {c110, c111}
    }

    // ---- Phase 3: lerp + store + accumulate ----
    float acc = 0.0f;
    #pragma unroll
    for (int j = 0; j < PTS; ++j) {
        const float c00 = v00[j].x * (1.0f - wz[j]) + v00[j].y * wz[j];
        const float c01 = v01[j].x * (1.0f - wz[j]) + v01[j].y * wz[j];
        const float c10 = v10[j].x * (1.0f - wz[j]) + v10[j].y * wz[j];
        const float c11 = v11[j].x * (1.0f - wz[j]) + v11[j].y * wz[j];
        const float c0 = c00 * (1.0f - wy[j]) + c01 * wy[j];
        const float c1 = c10 * (1.0f - wy[j]) + c11 * wy[j];
        const float v  = c0 * (1.0f - wx[j]) + c1 * wx[j];
        if (act[j]) {
            out[1 + i0 + j * T] = v;   // coalesced
            acc += v;
        }
    }

    // ---- Mean: wave64 shuffle -> LDS -> one atomic/block ----
    float s = acc;
    #pragma unroll
    for (int off = 32; off > 0; off >>= 1)
        s += __shfl_down(s, off, 64);

    __shared__ float wsum[4];  // 256 threads / 64 lanes
    const int lane = threadIdx.x & 63;
    const int wid  = threadIdx.x >> 6;
    if (lane == 0) wsum[wid] = s;
    __syncthreads();
    if (threadIdx.x == 0) {
        const float part = wsum[0] + wsum[1] + wsum[2] + wsum[3];
        atomicAdd(out, part * (1.0f / (float)N));
    }
}

extern "C" void kernel_launch(void* const* d_in, const int* in_sizes, int n_in,
                              void* d_out, int out_size, void* d_ws, size_t ws_size,
                              hipStream_t stream) {
    const float* pc1        = (const float*)d_in[0];
    const float* flow       = (const float*)d_in[1];
    const float* grid       = (const float*)d_in[2];
    const float* grid_min   = (const float*)d_in[3];
    const int*   grid_factor= (const int*)d_in[4];
    float* out = (float*)d_out;

    const int N = in_sizes[0] / 3;  // pc1 is [1, N, 3]

    // out[0] accumulates the mean via atomics; harness poisons d_out each call.
    hipMemsetAsync(d_out, 0, sizeof(float), stream);

    const int block = 256;
    const int threads_needed = (N + PTS - 1) / PTS;
    const int grid_sz = (threads_needed + block - 1) / block;
    dt_loss_kernel<<<grid_sz, block, 0, stream>>>(
        pc1, flow, grid, grid_min, grid_factor, out, N);
}